// Round 20
// baseline (318.324 us; speedup 1.0000x reference)
//
#include <hip/hip_runtime.h>
#include <math.h>

// Problem: B=128, P=128, D=128, N=4096, fp32 in/out.
// probs = softmax(10*tanh((A@K)/sqrt(128)) + mask) over n.
//
// R20: 64-VGPR diet of the R17 structure -> 4 blocks/CU (32 waves/CU TLP).
// R13-R19 audit: only ~80us of 228us is pipe-busy; rest is stall at 16
// waves/CU. VGPR<=64 doubles resident waves (m69 law). Diet: per-kb tr-read
// interleave (8 temps, not 32), no kreg dbuf, no mask prefetch regs.
//  K1: e = exp(10*tanh(score/sqrt(128)) + mask) -> O; row partials -> ws.
//      (max-free softmax: |10tanh| <= 10 -> e <= 2.3e4, sum <= 9e7)
//  K2: O *= 1/rowsum (32 partials per row, L3-assisted).
constexpr int BB = 128;
constexpr int PP = 128;
constexpr int DD = 128;
constexpr int NN = 4096;
constexpr float kC = 10.0f;
constexpr float k2InvSqrtD = 0.1767766952966369f;   // 2/sqrt(128)

constexpr int NTHR = 512;
constexpr int TEL = 272;             // f16 elems per 16x16 tile incl pad (544 B)

typedef float f32x4 __attribute__((ext_vector_type(4)));
typedef _Float16 f16x4 __attribute__((ext_vector_type(4)));
typedef _Float16 f16x8 __attribute__((ext_vector_type(8)));

__device__ __forceinline__ void st_nt_f4(float* p, float4 s) {
    f32x4 v = {s.x, s.y, s.z, s.w};
    __builtin_nontemporal_store(v, (f32x4*)p);
}

// Hardware transpose read (HW-verified R15): lane l (addr = tile + 8l)
// receives tile elems (l&15) + 16j + 64*(l>>4) of a row-major [16d][16n]
// tile: d_local = j + 4*(l>>4), n_local = l&15.
__device__ __forceinline__ f16x4 tr_read(unsigned addr) {
    f16x4 r;
    asm volatile("ds_read_b64_tr_b16 %0, %1" : "=v"(r) : "v"(addr));
    return r;
}

// z = 10*tanh(s/sqrt(128)) + m, via tanh(x) = 1 - 2/(e^{2x}+1)
__device__ __forceinline__ float clip1(float s, float m) {
    const float e2 = __expf(s * k2InvSqrtD);
    const float r = __builtin_amdgcn_rcpf(e2 + 1.0f);
    return fmaf(-2.0f * kC, r, kC) + m;
}

// ===================== Kernel 1: staged GEMM + clip + exp =====================
// Grid: 4096 = 128 b x 32 n-tiles(128 cols). 512 thr = 8 waves; wave w owns
// rows w*16..+15, 128 cols as 2 halves x 4 nts.
// fp16x3: score = hh + hl + lh; k-packing d = kb*32 + 4g + (j&3) + 16*(j>>2)
// identical on A (regs) and B (tr reads) -> k-permutation errors cancel.
// C/D layout (HW-verified): col = lane&15, row = 4*(lane>>4) + reg.
// LDS: ONE half-buffer (128d x 64n) as 8x4 grid of 16x16 hi/lo tiles;
// tr reads conflict-free (R15-R19: SQ_LDS_BANK_CONFLICT = 0).
__global__ __launch_bounds__(NTHR, 4)    // cap 64 VGPR; structure dieted to ~58
void score_kernel(const float* __restrict__ A,   // [B][P][D]
                  const float* __restrict__ K,   // [B][D][N]
                  const float* __restrict__ M,   // [B][P][N]
                  float* __restrict__ O,         // [B][P][N] <- exp(z)
                  float* __restrict__ ws) {      // [B*P][32] partial row sums
    __shared__ _Float16 Khi[32 * TEL];           // 17.4 KB
    __shared__ _Float16 Klo[32 * TEL];           // 17.4 KB

    const int l = blockIdx.x;
    const int b = l >> 5;
    const int ntb = l & 31;
    const int n_base = ntb * 128;

    const int tid = (int)threadIdx.x;
    const int lane = tid & 63;
    const int wid = tid >> 6;
    const int col = lane & 15;             // A row-in-frag / B col / C col
    const int g = lane >> 4;               // k-group / C row group
    const int kbase = 4 * g;

    // ---- A fragments (regs, whole kernel): 16 rows x 128 d per wave ----
    const float* Arow = A + (size_t)(b * PP + wid * 16 + col) * DD;
    f16x8 ah[4], al[4];
    #pragma unroll
    for (int kb = 0; kb < 4; ++kb) {
        #pragma unroll
        for (int j = 0; j < 8; ++j) {
            const int d = kb * 32 + kbase + (j & 3) + 16 * (j >> 2);
            const float x = Arow[d];
            const _Float16 h = (_Float16)x;
            ah[kb][j] = h;
            al[kb][j] = (_Float16)(x - (float)h);
        }
    }

    const size_t mrow0 = (size_t)(b * PP + wid * 16 + kbase) * NN + n_base + col;
    const unsigned khi0 = (unsigned)(uintptr_t)&Khi[0] + (unsigned)lane * 8u;
    const unsigned klo0 = (unsigned)(uintptr_t)&Klo[0] + (unsigned)lane * 8u;

    const float* Kg = K + (size_t)b * DD * NN + n_base;
    const int nl4 = (tid & 15) * 4;        // 4 consecutive n within the half
    const int d0 = tid >> 4;               // base d (0..31)
    const int el0 = ((d0 >> 4) * 4 + (nl4 >> 4)) * TEL + (d0 & 15) * 16 + (nl4 & 12);

    float rsum[4] = {0.f, 0.f, 0.f, 0.f};

    #pragma unroll
    for (int half = 0; half < 2; ++half) {
        if (half) __syncthreads();         // all reads of prev half done

        // ---- stage this half's K (128 d x 64 n) hi/lo, b64 writes ----
        // (transient kreg regs die before the nt loop; TLP covers the latency)
        #pragma unroll
        for (int i = 0; i < 4; ++i) {
            const float4 v = *(const float4*)(Kg + (size_t)(d0 + 32 * i) * NN
                                              + half * 64 + nl4);
            const float xs[4] = {v.x, v.y, v.z, v.w};
            f16x4 h, lo;
            #pragma unroll
            for (int e = 0; e < 4; ++e) {
                const _Float16 hh = (_Float16)xs[e];
                h[e] = hh;
                lo[e] = (_Float16)(xs[e] - (float)hh);
            }
            const int el = el0 + i * 8 * TEL;
            *(f16x4*)&Khi[el] = h;
            *(f16x4*)&Klo[el] = lo;
        }
        __syncthreads();

        // ---- 4 n-subtiles of this half ----
        #pragma unroll
        for (int nt2 = 0; nt2 < 4; ++nt2) {
            const int nt = half * 4 + nt2;

            f32x4 acc = {0.f, 0.f, 0.f, 0.f};
            // per-kb interleave: 4 tr reads (8 VGPR temps) -> wait -> 3 MFMA
            #pragma unroll
            for (int kb = 0; kb < 4; ++kb) {
                const unsigned t0 = (unsigned)(((2 * kb) * 4 + nt2) * 544);
                const f16x4 bh0 = tr_read(khi0 + t0);
                const f16x4 bh1 = tr_read(khi0 + t0 + 4u * 544u);
                const f16x4 bl0 = tr_read(klo0 + t0);
                const f16x4 bl1 = tr_read(klo0 + t0 + 4u * 544u);
                asm volatile("s_waitcnt lgkmcnt(0)" ::: "memory");
                __builtin_amdgcn_sched_barrier(0);     // rule #18
                const f16x8 bh = __builtin_shufflevector(bh0, bh1, 0, 1, 2, 3, 4, 5, 6, 7);
                const f16x8 bl = __builtin_shufflevector(bl0, bl1, 0, 1, 2, 3, 4, 5, 6, 7);
                acc = __builtin_amdgcn_mfma_f32_16x16x32_f16(ah[kb], bh, acc, 0, 0, 0);
                acc = __builtin_amdgcn_mfma_f32_16x16x32_f16(ah[kb], bl, acc, 0, 0, 0);
                acc = __builtin_amdgcn_mfma_f32_16x16x32_f16(al[kb], bh, acc, 0, 0, 0);
            }

            // epilogue: e = exp(clip + mask); store; partials (M loaded here;
            // latency covered by 32 waves/CU TLP)
            #pragma unroll
            for (int j = 0; j < 4; ++j) {
                const size_t off = mrow0 + (size_t)j * NN + nt * 16;
                const float e = __expf(clip1(acc[j], M[off]));
                O[off] = e;                // cached: K2 re-reads via L2/L3
                rsum[j] += e;
            }
        }
    }

    // ---- reduce row partials across the 16 cols of each group -> ws ----
    #pragma unroll
    for (int j = 0; j < 4; ++j) {
        float s = rsum[j];
        s += __shfl_xor(s, 1);
        s += __shfl_xor(s, 2);
        s += __shfl_xor(s, 4);
        s += __shfl_xor(s, 8);
        rsum[j] = s;
    }
    if (col == 0) {
        #pragma unroll
        for (int j = 0; j < 4; ++j)
            ws[(size_t)(b * PP + wid * 16 + kbase + j) * 32 + ntb] = rsum[j];
    }
}

// ========================= Kernel 2: scale by 1/rowsum ========================
// Pure streaming: 2048 blocks x 256 thr; 32 threads/row, 32 f4/thread.
__global__ __launch_bounds__(256, 4)
void scale_kernel(float* __restrict__ O, const float* __restrict__ ws) {
    const int gtid = blockIdx.x * 256 + (int)threadIdx.x;
    const int row = gtid >> 5;
    const int seg = gtid & 31;

    const float* w = ws + (size_t)row * 32;
    float s = 0.f;
    #pragma unroll
    for (int i = 0; i < 8; ++i) {
        const float4 v = *(const float4*)(w + i * 4);
        s += (v.x + v.y) + (v.z + v.w);
    }
    const float inv = __builtin_amdgcn_rcpf(s);

    float4* R = (float4*)(O + (size_t)row * NN);
    #pragma unroll 8
    for (int i = 0; i < 32; ++i) {
        const int idx = i * 32 + seg;      // lanes consecutive -> coalesced
        float4 v = R[idx];
        v.x *= inv; v.y *= inv; v.z *= inv; v.w *= inv;
        st_nt_f4((float*)&R[idx], v);
    }
}

extern "C" void kernel_launch(void* const* d_in, const int* in_sizes, int n_in,
                              void* d_out, int out_size, void* d_ws, size_t ws_size,
                              hipStream_t stream) {
    const float* A = (const float*)d_in[0];   // mh_attn_out [128][128][128]
    const float* K = (const float*)d_in[1];   // single_head_key [128][128][4096]
    const float* M = (const float*)d_in[2];   // mask [128][128][4096]
    float* O = (float*)d_out;                 // probs [128][128][4096]
    float* ws = (float*)d_ws;                 // 16384 rows x 32 partials = 2 MB

    score_kernel<<<dim3(BB * 32), dim3(NTHR), 0, stream>>>(A, K, M, O, ws);
    scale_kernel<<<dim3(2048), dim3(256), 0, stream>>>(O, ws);
}

// Round 21
// 273.319 us; speedup vs baseline: 1.1647x; 1.1647x over previous
//
#include <hip/hip_runtime.h>
#include <math.h>

// Problem: B=128, P=128, D=128, N=4096, fp32 in/out.
// probs = softmax(10*tanh((A@K)/sqrt(128)) + mask) over n.
//
// R21: clean TLP test. R20's diet (proven ~64-68 VGPR demand) + rolling mask
// prefetch (+8) under launch_bounds(512,3) -> cap 85, THREE blocks/CU with
// zero spill headroom (R20 failed by spilling at the 64-cap cliff).
//  K1: e = exp(10*tanh(score/sqrt(128)) + mask) -> O; row partials -> ws.
//      (max-free softmax: |10tanh| <= 10 -> e <= 2.3e4, sum <= 9e7)
//  K2: O *= 1/rowsum (32 partials per row).
constexpr int BB = 128;
constexpr int PP = 128;
constexpr int DD = 128;
constexpr int NN = 4096;
constexpr float kC = 10.0f;
constexpr float k2InvSqrtD = 0.1767766952966369f;   // 2/sqrt(128)

constexpr int NTHR = 512;
constexpr int TEL = 272;             // f16 elems per 16x16 tile incl pad (544 B)

typedef float f32x4 __attribute__((ext_vector_type(4)));
typedef _Float16 f16x4 __attribute__((ext_vector_type(4)));
typedef _Float16 f16x8 __attribute__((ext_vector_type(8)));

__device__ __forceinline__ void st_nt_f4(float* p, float4 s) {
    f32x4 v = {s.x, s.y, s.z, s.w};
    __builtin_nontemporal_store(v, (f32x4*)p);
}

// Hardware transpose read (HW-verified R15): lane l (addr = tile + 8l)
// receives tile elems (l&15) + 16j + 64*(l>>4) of a row-major [16d][16n]
// tile: d_local = j + 4*(l>>4), n_local = l&15.
__device__ __forceinline__ f16x4 tr_read(unsigned addr) {
    f16x4 r;
    asm volatile("ds_read_b64_tr_b16 %0, %1" : "=v"(r) : "v"(addr));
    return r;
}

// z = 10*tanh(s/sqrt(128)) + m, via tanh(x) = 1 - 2/(e^{2x}+1)
__device__ __forceinline__ float clip1(float s, float m) {
    const float e2 = __expf(s * k2InvSqrtD);
    const float r = __builtin_amdgcn_rcpf(e2 + 1.0f);
    return fmaf(-2.0f * kC, r, kC) + m;
}

// ===================== Kernel 1: staged GEMM + clip + exp =====================
// Grid: 4096 = 128 b x 32 n-tiles(128 cols). 512 thr = 8 waves; wave w owns
// rows w*16..+15, 128 cols as 2 halves x 4 nts.
// fp16x3: score = hh + hl + lh; k-packing d = kb*32 + 4g + (j&3) + 16*(j>>2)
// identical on A (regs) and B (tr reads) -> k-permutation errors cancel.
// C/D layout (HW-verified): col = lane&15, row = 4*(lane>>4) + reg.
// LDS: ONE half-buffer (128d x 64n) as 8x4 grid of 16x16 hi/lo tiles;
// tr reads conflict-free (R15-R20: SQ_LDS_BANK_CONFLICT = 0).
__global__ __launch_bounds__(NTHR, 3)    // cap 85 VGPR; design ~76 live
void score_kernel(const float* __restrict__ A,   // [B][P][D]
                  const float* __restrict__ K,   // [B][D][N]
                  const float* __restrict__ M,   // [B][P][N]
                  float* __restrict__ O,         // [B][P][N] <- exp(z)
                  float* __restrict__ ws) {      // [B*P][32] partial row sums
    __shared__ _Float16 Khi[32 * TEL];           // 17.4 KB
    __shared__ _Float16 Klo[32 * TEL];           // 17.4 KB

    const int l = blockIdx.x;
    const int b = l >> 5;
    const int ntb = l & 31;
    const int n_base = ntb * 128;

    const int tid = (int)threadIdx.x;
    const int lane = tid & 63;
    const int wid = tid >> 6;
    const int col = lane & 15;             // A row-in-frag / B col / C col
    const int g = lane >> 4;               // k-group / C row group
    const int kbase = 4 * g;

    // ---- A fragments (regs, whole kernel): 16 rows x 128 d per wave ----
    const float* Arow = A + (size_t)(b * PP + wid * 16 + col) * DD;
    f16x8 ah[4], al[4];
    #pragma unroll
    for (int kb = 0; kb < 4; ++kb) {
        #pragma unroll
        for (int j = 0; j < 8; ++j) {
            const int d = kb * 32 + kbase + (j & 3) + 16 * (j >> 2);
            const float x = Arow[d];
            const _Float16 h = (_Float16)x;
            ah[kb][j] = h;
            al[kb][j] = (_Float16)(x - (float)h);
        }
    }

    const size_t mrow0 = (size_t)(b * PP + wid * 16 + kbase) * NN + n_base + col;
    const unsigned khi0 = (unsigned)(uintptr_t)&Khi[0] + (unsigned)lane * 8u;
    const unsigned klo0 = (unsigned)(uintptr_t)&Klo[0] + (unsigned)lane * 8u;

    const float* Kg = K + (size_t)b * DD * NN + n_base;
    const int nl4 = (tid & 15) * 4;        // 4 consecutive n within the half
    const int d0 = tid >> 4;               // base d (0..31)
    const int el0 = ((d0 >> 4) * 4 + (nl4 >> 4)) * TEL + (d0 & 15) * 16 + (nl4 & 12);

    float rsum[4] = {0.f, 0.f, 0.f, 0.f};

    // rolling 2-deep mask prefetch (8 regs)
    float mv[4], mvn[4];
    #pragma unroll
    for (int j = 0; j < 4; ++j) mv[j] = M[mrow0 + (size_t)j * NN];
    #pragma unroll
    for (int j = 0; j < 4; ++j) mvn[j] = M[mrow0 + (size_t)j * NN + 16];

    #pragma unroll
    for (int half = 0; half < 2; ++half) {
        if (half) __syncthreads();         // all reads of prev half done

        // ---- stage this half's K (128 d x 64 n) hi/lo, b64 writes ----
        #pragma unroll
        for (int i = 0; i < 4; ++i) {
            const float4 v = *(const float4*)(Kg + (size_t)(d0 + 32 * i) * NN
                                              + half * 64 + nl4);
            const float xs[4] = {v.x, v.y, v.z, v.w};
            f16x4 h, lo;
            #pragma unroll
            for (int e = 0; e < 4; ++e) {
                const _Float16 hh = (_Float16)xs[e];
                h[e] = hh;
                lo[e] = (_Float16)(xs[e] - (float)hh);
            }
            const int el = el0 + i * 8 * TEL;
            *(f16x4*)&Khi[el] = h;
            *(f16x4*)&Klo[el] = lo;
        }
        __syncthreads();

        // ---- 4 n-subtiles of this half ----
        #pragma unroll
        for (int nt2 = 0; nt2 < 4; ++nt2) {
            const int nt = half * 4 + nt2;

            f32x4 acc = {0.f, 0.f, 0.f, 0.f};
            // per-kb interleave: 4 tr reads (8 VGPR temps) -> wait -> 3 MFMA
            #pragma unroll
            for (int kb = 0; kb < 4; ++kb) {
                const unsigned t0 = (unsigned)(((2 * kb) * 4 + nt2) * 544);
                const f16x4 bh0 = tr_read(khi0 + t0);
                const f16x4 bh1 = tr_read(khi0 + t0 + 4u * 544u);
                const f16x4 bl0 = tr_read(klo0 + t0);
                const f16x4 bl1 = tr_read(klo0 + t0 + 4u * 544u);
                asm volatile("s_waitcnt lgkmcnt(0)" ::: "memory");
                __builtin_amdgcn_sched_barrier(0);     // rule #18
                const f16x8 bh = __builtin_shufflevector(bh0, bh1, 0, 1, 2, 3, 4, 5, 6, 7);
                const f16x8 bl = __builtin_shufflevector(bl0, bl1, 0, 1, 2, 3, 4, 5, 6, 7);
                acc = __builtin_amdgcn_mfma_f32_16x16x32_f16(ah[kb], bh, acc, 0, 0, 0);
                acc = __builtin_amdgcn_mfma_f32_16x16x32_f16(ah[kb], bl, acc, 0, 0, 0);
                acc = __builtin_amdgcn_mfma_f32_16x16x32_f16(al[kb], bh, acc, 0, 0, 0);
            }

            // epilogue: e = exp(clip + mask); store; partials
            #pragma unroll
            for (int j = 0; j < 4; ++j) {
                const size_t off = mrow0 + (size_t)j * NN + nt * 16;
                const float e = __expf(clip1(acc[j], mv[j]));
                O[off] = e;                // cached: K2 re-reads via L2/L3
                rsum[j] += e;
            }

            // rotate mask pipeline (distance 2)
            #pragma unroll
            for (int j = 0; j < 4; ++j) mv[j] = mvn[j];
            if (nt + 2 < 8) {
                #pragma unroll
                for (int j = 0; j < 4; ++j)
                    mvn[j] = M[mrow0 + (size_t)j * NN + (nt + 2) * 16];
            }
        }
    }

    // ---- reduce row partials across the 16 cols of each group -> ws ----
    #pragma unroll
    for (int j = 0; j < 4; ++j) {
        float s = rsum[j];
        s += __shfl_xor(s, 1);
        s += __shfl_xor(s, 2);
        s += __shfl_xor(s, 4);
        s += __shfl_xor(s, 8);
        rsum[j] = s;
    }
    if (col == 0) {
        #pragma unroll
        for (int j = 0; j < 4; ++j)
            ws[(size_t)(b * PP + wid * 16 + kbase + j) * 32 + ntb] = rsum[j];
    }
}

// ========================= Kernel 2: scale by 1/rowsum ========================
// Pure streaming: 2048 blocks x 256 thr; 32 threads/row, 32 f4/thread.
__global__ __launch_bounds__(256, 4)
void scale_kernel(float* __restrict__ O, const float* __restrict__ ws) {
    const int gtid = blockIdx.x * 256 + (int)threadIdx.x;
    const int row = gtid >> 5;
    const int seg = gtid & 31;

    const float* w = ws + (size_t)row * 32;
    float s = 0.f;
    #pragma unroll
    for (int i = 0; i < 8; ++i) {
        const float4 v = *(const float4*)(w + i * 4);
        s += (v.x + v.y) + (v.z + v.w);
    }
    const float inv = __builtin_amdgcn_rcpf(s);

    float4* R = (float4*)(O + (size_t)row * NN);
    #pragma unroll 8
    for (int i = 0; i < 32; ++i) {
        const int idx = i * 32 + seg;      // lanes consecutive -> coalesced
        float4 v = R[idx];
        v.x *= inv; v.y *= inv; v.z *= inv; v.w *= inv;
        st_nt_f4((float*)&R[idx], v);
    }
}

extern "C" void kernel_launch(void* const* d_in, const int* in_sizes, int n_in,
                              void* d_out, int out_size, void* d_ws, size_t ws_size,
                              hipStream_t stream) {
    const float* A = (const float*)d_in[0];   // mh_attn_out [128][128][128]
    const float* K = (const float*)d_in[1];   // single_head_key [128][128][4096]
    const float* M = (const float*)d_in[2];   // mask [128][128][4096]
    float* O = (float*)d_out;                 // probs [128][128][4096]
    float* ws = (float*)d_ws;                 // 16384 rows x 32 partials = 2 MB

    score_kernel<<<dim3(BB * 32), dim3(NTHR), 0, stream>>>(A, K, M, O, ws);
    scale_kernel<<<dim3(2048), dim3(256), 0, stream>>>(O, ws);
}